// Round 1
// baseline (158.148 us; speedup 1.0000x reference)
//
#include <hip/hip_runtime.h>
#include <cstdint>
#include <cstddef>

#define NPTS   4096
#define BATCH  4
#define KNN    8
#define NCHUNK 8
#define CH     (NPTS / NCHUNK)   // 512
#define EPS_F  1e-12f

__device__ __forceinline__ uint32_t u32min(uint32_t a, uint32_t b) { return a < b ? a : b; }
__device__ __forceinline__ uint32_t u32max(uint32_t a, uint32_t b) { return a > b ? a : b; }
__device__ __forceinline__ unsigned long long u64min(unsigned long long a, unsigned long long b) { return a < b ? a : b; }
__device__ __forceinline__ unsigned long long u64max(unsigned long long a, unsigned long long b) { return a > b ? a : b; }

// ---------------------------------------------------------------------------
// Kernel 1: per-(cloud, batch, point, chunk) partial top-8 by truncated d2 key.
// Key = top-20 bits of (float_bits(d2) << 1) | 12-bit candidate index.
// Monotone in d2 (hence in dist); ties broken by ascending index (matches
// lax.top_k tie-breaking). Self excluded explicitly.
// ---------------------------------------------------------------------------
extern "C" __global__ void __launch_bounds__(256)
knn_partial_kernel(const float* __restrict__ pred, const float* __restrict__ tgt,
                   uint32_t* __restrict__ partial) {
  int bx = blockIdx.x;
  const int chunk = bx & (NCHUNK - 1); bx >>= 3;
  const int ig    = bx & 15;           bx >>= 4;
  const int b     = bx & 3;            bx >>= 2;
  const int cloud = bx;  // 0 = pred, 1 = target

  const float* __restrict__ pts = (cloud ? tgt : pred) + (size_t)b * NPTS * 3;
  const int i = ig * 256 + threadIdx.x;

  const float xix = pts[3 * i + 0];
  const float xiy = pts[3 * i + 1];
  const float xiz = pts[3 * i + 2];

  uint32_t loc[KNN];
#pragma unroll
  for (int k = 0; k < KNN; ++k) loc[k] = 0xFFFFFFFFu;

  const int j0 = chunk * CH;
#pragma unroll 4
  for (int t = 0; t < CH; ++t) {
    const int j = j0 + t;
    // Uniform address across the whole block -> scalar/broadcast load.
    const float cx = pts[3 * j + 0];
    const float cy = pts[3 * j + 1];
    const float cz = pts[3 * j + 2];
    const float dx = xix - cx, dy = xiy - cy, dz = xiz - cz;
    const float d2 = fmaf(dx, dx, fmaf(dy, dy, dz * dz));
    uint32_t key = ((__float_as_uint(d2) << 1) & 0xFFFFF000u) | (uint32_t)j;
    key = (j == i) ? 0xFFFFFFFFu : key;
    // Branchless sorted insert (ascending), drops the largest.
    uint32_t x = key;
#pragma unroll
    for (int m = 0; m < KNN; ++m) {
      const uint32_t lo = u32min(loc[m], x);
      x = u32max(loc[m], x);
      loc[m] = lo;
    }
  }

  // Layout: [cloud][b][chunk][NPTS][KNN] -> coalesced 32B/thread writes.
  uint32_t* p = partial +
      ((((size_t)(cloud * BATCH + b) * NCHUNK + chunk) * NPTS) + (size_t)i) * KNN;
#pragma unroll
  for (int k = 0; k < KNN; ++k) p[k] = loc[k];
}

// ---------------------------------------------------------------------------
// Merge NCHUNK sorted 8-lists (truncated keys) into the final top-8.
// ---------------------------------------------------------------------------
__device__ __forceinline__ void merge_list(const uint32_t* __restrict__ base, int i,
                                           uint32_t out[KNN]) {
#pragma unroll
  for (int k = 0; k < KNN; ++k) out[k] = 0xFFFFFFFFu;
#pragma unroll
  for (int c = 0; c < NCHUNK; ++c) {
    const uint32_t* p = base + ((size_t)c * NPTS + (size_t)i) * KNN;
#pragma unroll
    for (int k = 0; k < KNN; ++k) {
      uint32_t x = p[k];
#pragma unroll
      for (int m = 0; m < KNN; ++m) {
        const uint32_t lo = u32min(out[m], x);
        x = u32max(out[m], x);
        out[m] = lo;
      }
    }
  }
}

// Batcher odd-even mergesort for 8 elements: 19 compare-exchanges.
__device__ __forceinline__ void sort8(unsigned long long s[8]) {
#define CE(a, b) { unsigned long long lo = u64min(s[a], s[b]); \
                   unsigned long long hi = u64max(s[a], s[b]); s[a] = lo; s[b] = hi; }
  CE(0,1) CE(2,3) CE(0,2) CE(1,3) CE(1,2)   // sort 0..3
  CE(4,5) CE(6,7) CE(4,6) CE(5,7) CE(5,6)   // sort 4..7
  CE(0,4) CE(1,5) CE(2,6) CE(3,7)           // odd-even merge
  CE(2,4) CE(3,5)
  CE(1,2) CE(3,4) CE(5,6)
#undef CE
}

// ---------------------------------------------------------------------------
// Kernel 2: per-point loss terms. Re-computes exact distances with the
// reference's sq_i + sq_j - 2*dot formula, re-sorts by exact (dist, idx),
// then computes density / direction / curvature contributions; block-reduces
// and atomically accumulates into double acc[3].
// ---------------------------------------------------------------------------
extern "C" __global__ void __launch_bounds__(256)
loss_kernel(const float* __restrict__ pred, const float* __restrict__ tgt,
            const uint32_t* __restrict__ partial, double* __restrict__ acc) {
  const int p = blockIdx.x * 256 + threadIdx.x;   // 0 .. 16383
  const int b = p >> 12;
  const int i = p & (NPTS - 1);

  const float* __restrict__ P = pred + (size_t)b * NPTS * 3;
  const float* __restrict__ T = tgt  + (size_t)b * NPTS * 3;

  uint32_t mp[KNN], mt[KNN];
  merge_list(partial + (size_t)(0 * BATCH + b) * NCHUNK * NPTS * KNN, i, mp);
  merge_list(partial + (size_t)(1 * BATCH + b) * NCHUNK * NPTS * KNN, i, mt);

  const float pix = P[3 * i], piy = P[3 * i + 1], piz = P[3 * i + 2];
  const float tix = T[3 * i], tiy = T[3 * i + 1], tiz = T[3 * i + 2];
  const float sqp = pix * pix + piy * piy + piz * piz;
  const float sqt = tix * tix + tiy * tiy + tiz * tiz;

  // Exact sort keys: (float_bits(dist) << 12) | idx  — 44 bits, monotone.
  unsigned long long kp[KNN], kt[KNN];
#pragma unroll
  for (int k = 0; k < KNN; ++k) {
    {
      const int j = (int)(mp[k] & 0xFFFu);
      const float x = P[3 * j], y = P[3 * j + 1], z = P[3 * j + 2];
      const float d2 = sqp + (x * x + y * y + z * z)
                       - 2.0f * (pix * x + piy * y + piz * z);
      const float dist = sqrtf(fmaxf(d2, EPS_F));
      kp[k] = ((unsigned long long)__float_as_uint(dist) << 12) | (unsigned long long)j;
    }
    {
      const int j = (int)(mt[k] & 0xFFFu);
      const float x = T[3 * j], y = T[3 * j + 1], z = T[3 * j + 2];
      const float d2 = sqt + (x * x + y * y + z * z)
                       - 2.0f * (tix * x + tiy * y + tiz * z);
      const float dist = sqrtf(fmaxf(d2, EPS_F));
      kt[k] = ((unsigned long long)__float_as_uint(dist) << 12) | (unsigned long long)j;
    }
  }
  sort8(kp);
  sort8(kt);

  float dsp = 0.f, dst = 0.f, sdot = 0.f;
  float pxx = 0, pyy = 0, pzz = 0, pxy = 0, pxz = 0, pyz = 0;
  float txx = 0, tyy = 0, tzz = 0, txy = 0, txz = 0, tyz = 0;
#pragma unroll
  for (int k = 0; k < KNN; ++k) {
    const int jp = (int)(kp[k] & 0xFFFu);
    dsp += __uint_as_float((uint32_t)(kp[k] >> 12));
    const float ax = P[3 * jp] - pix, ay = P[3 * jp + 1] - piy, az = P[3 * jp + 2] - piz;
    const float an = sqrtf(ax * ax + ay * ay + az * az);
    const float ai = 1.0f / fmaxf(an, EPS_F);
    pxx += ax * ax; pyy += ay * ay; pzz += az * az;
    pxy += ax * ay; pxz += ax * az; pyz += ay * az;

    const int jt = (int)(kt[k] & 0xFFFu);
    dst += __uint_as_float((uint32_t)(kt[k] >> 12));
    const float bx = T[3 * jt] - tix, by = T[3 * jt + 1] - tiy, bz = T[3 * jt + 2] - tiz;
    const float bn = sqrtf(bx * bx + by * by + bz * bz);
    const float bi = 1.0f / fmaxf(bn, EPS_F);
    txx += bx * bx; tyy += by * by; tzz += bz * bz;
    txy += bx * by; txz += bx * bz; tyz += by * bz;

    sdot += (ax * bx + ay * by + az * bz) * (ai * bi);
  }

  const float densp = dsp * (1.0f / KNN);
  const float denst = dst * (1.0f / KNN);
  float e = (densp - denst) * (densp - denst);

  const float dxx = (pxx - txx) * (1.0f / KNN);
  const float dyy = (pyy - tyy) * (1.0f / KNN);
  const float dzz = (pzz - tzz) * (1.0f / KNN);
  const float dxy = (pxy - txy) * (1.0f / KNN);
  const float dxz = (pxz - txz) * (1.0f / KNN);
  const float dyz = (pyz - tyz) * (1.0f / KNN);
  float cfro = sqrtf(dxx * dxx + dyy * dyy + dzz * dzz
                     + 2.0f * (dxy * dxy + dxz * dxz + dyz * dyz));
  float s = sdot;

  // Block reduction: wave shuffle, then LDS across 4 waves, one atomic/block.
#pragma unroll
  for (int off = 32; off > 0; off >>= 1) {
    e    += __shfl_down(e, off);
    s    += __shfl_down(s, off);
    cfro += __shfl_down(cfro, off);
  }
  __shared__ float re[4], rs[4], rc[4];
  const int w = threadIdx.x >> 6;
  if ((threadIdx.x & 63) == 0) { re[w] = e; rs[w] = s; rc[w] = cfro; }
  __syncthreads();
  if (threadIdx.x == 0) {
    atomicAdd(&acc[0], (double)(re[0] + re[1] + re[2] + re[3]));
    atomicAdd(&acc[1], (double)(rs[0] + rs[1] + rs[2] + rs[3]));
    atomicAdd(&acc[2], (double)(rc[0] + rc[1] + rc[2] + rc[3]));
  }
}

extern "C" __global__ void finalize_kernel(const double* __restrict__ acc,
                                           float* __restrict__ out) {
  const double BN = (double)BATCH * (double)NPTS;
  const double density   = acc[0] / BN;
  const double direction = 1.0 - acc[1] / (BN * (double)KNN);
  const double curvature = acc[2] / BN;
  out[0] = (float)(density + 0.5 * direction + 0.5 * curvature);
}

extern "C" void kernel_launch(void* const* d_in, const int* in_sizes, int n_in,
                              void* d_out, int out_size, void* d_ws, size_t ws_size,
                              hipStream_t stream) {
  const float* pred = (const float*)d_in[0];
  const float* tgt  = (const float*)d_in[1];
  double* acc = (double*)d_ws;
  uint32_t* partial = (uint32_t*)((char*)d_ws + 256);

  hipMemsetAsync(acc, 0, 32, stream);

  // 2 clouds x 4 batches x 16 point-groups x 8 chunks = 1024 blocks
  knn_partial_kernel<<<2 * BATCH * (NPTS / 256) * NCHUNK, 256, 0, stream>>>(pred, tgt, partial);
  // 16384 points / 256 = 64 blocks
  loss_kernel<<<(BATCH * NPTS) / 256, 256, 0, stream>>>(pred, tgt, partial, acc);
  finalize_kernel<<<1, 1, 0, stream>>>(acc, (float*)d_out);
}

// Round 2
// 132.381 us; speedup vs baseline: 1.1946x; 1.1946x over previous
//
#include <hip/hip_runtime.h>
#include <cstdint>
#include <cstddef>

#define NPTS   4096
#define BATCH  4
#define KNN    8
#define EPS_F  1e-12f

__device__ __forceinline__ uint32_t u32min(uint32_t a, uint32_t b) { return a < b ? a : b; }
__device__ __forceinline__ uint32_t u32max(uint32_t a, uint32_t b) { return a > b ? a : b; }
__device__ __forceinline__ unsigned long long u64min(unsigned long long a, unsigned long long b) { return a < b ? a : b; }
__device__ __forceinline__ unsigned long long u64max(unsigned long long a, unsigned long long b) { return a > b ? a : b; }

// v_med3_u32: median of 3. For sorted a<=b, med3(a,b,x) == clamp(x,a,b) — one
// instruction instead of min+max (compiler can't prove a<=b, so asm it).
__device__ __forceinline__ uint32_t umed3(uint32_t a, uint32_t b, uint32_t c) {
  uint32_t d;
  asm("v_med3_u32 %0, %1, %2, %3" : "=v"(d) : "v"(a), "v"(b), "v"(c));
  return d;
}

// Insert key into ascending 9-list, dropping the largest.
// loc'[0]=min(loc[0],key); loc'[m]=med3(loc[m-1],loc[m],key) — 9 independent ops.
__device__ __forceinline__ void insert9(uint32_t loc[KNN + 1], uint32_t key) {
  uint32_t prev = loc[0];
  loc[0] = u32min(prev, key);
#pragma unroll
  for (int m = 1; m <= KNN; ++m) {
    const uint32_t cur = loc[m];
    loc[m] = umed3(prev, cur, key);
    prev = cur;
  }
}

// ---------------------------------------------------------------------------
// Kernel 1: per-(cloud,batch,point,chunk) top-9 (incl. self) by truncated key.
// Key = (float_bits(d2) & 0xFFFFF000) | j  (d2>=0 so bits are monotone; ties
// break by ascending j, matching lax.top_k). Self (d2==0) is always rank-0 of
// its own chunk; output drops it there (block-uniform predicate).
// Candidates read as uniform-address float4 (SGPR base + imm offsets).
// ---------------------------------------------------------------------------
template <int NC>
__global__ void __launch_bounds__(256)
knn_partial_t(const float* __restrict__ pred, const float* __restrict__ tgt,
              uint32_t* __restrict__ partial) {
  constexpr int CHN = NPTS / NC;
  int bx = blockIdx.x;
  const int chunk = bx % NC; bx /= NC;
  const int ig    = bx & 15; bx >>= 4;
  const int b     = bx & 3;  bx >>= 2;
  const int cloud = bx;  // 0 = pred, 1 = target

  const float* __restrict__ pts = (cloud ? tgt : pred) + (size_t)b * NPTS * 3;
  const int tid = threadIdx.x;
  const int i = ig * 256 + tid;
  const int j0 = chunk * CHN;

  const float xix = pts[3 * i + 0];
  const float xiy = pts[3 * i + 1];
  const float xiz = pts[3 * i + 2];

  uint32_t loc[KNN + 1];
#pragma unroll
  for (int k = 0; k <= KNN; ++k) loc[k] = 0xFFFFFFFFu;

  // j0*3*4 bytes is 16B-aligned (j0 multiple of 256).
  const float4* __restrict__ c4 = (const float4*)(pts + 3 * j0);

#pragma unroll 2
  for (int t4 = 0; t4 < CHN / 4; ++t4) {
    // 3 x float4 = 4 candidates (xyz interleaved); deswizzle is register naming.
    const float4 q0 = c4[3 * t4 + 0];  // x0 y0 z0 x1
    const float4 q1 = c4[3 * t4 + 1];  // y1 z1 x2 y2
    const float4 q2 = c4[3 * t4 + 2];  // z2 x3 y3 z3
    const int jb = j0 + 4 * t4;
    {
      const float dx = xix - q0.x, dy = xiy - q0.y, dz = xiz - q0.z;
      const float d2 = dx * dx + dy * dy + dz * dz;
      insert9(loc, (__float_as_uint(d2) & 0xFFFFF000u) | (uint32_t)(jb + 0));
    }
    {
      const float dx = xix - q0.w, dy = xiy - q1.x, dz = xiz - q1.y;
      const float d2 = dx * dx + dy * dy + dz * dz;
      insert9(loc, (__float_as_uint(d2) & 0xFFFFF000u) | (uint32_t)(jb + 1));
    }
    {
      const float dx = xix - q1.z, dy = xiy - q1.w, dz = xiz - q2.x;
      const float d2 = dx * dx + dy * dy + dz * dz;
      insert9(loc, (__float_as_uint(d2) & 0xFFFFF000u) | (uint32_t)(jb + 2));
    }
    {
      const float dx = xix - q2.y, dy = xiy - q2.z, dz = xiz - q2.w;
      const float d2 = dx * dx + dy * dy + dz * dz;
      insert9(loc, (__float_as_uint(d2) & 0xFFFFF000u) | (uint32_t)(jb + 3));
    }
  }

  // Block-uniform: does this chunk contain this block's i-range? (CHN >= 256)
  const bool self_chunk = ((ig * 256) / CHN) == chunk;
  uint4 o0, o1;
  if (self_chunk) {
    o0 = make_uint4(loc[1], loc[2], loc[3], loc[4]);
    o1 = make_uint4(loc[5], loc[6], loc[7], loc[8]);
  } else {
    o0 = make_uint4(loc[0], loc[1], loc[2], loc[3]);
    o1 = make_uint4(loc[4], loc[5], loc[6], loc[7]);
  }
  uint32_t* p = partial +
      ((((size_t)(cloud * BATCH + b) * NC + chunk) * NPTS) + (size_t)i) * KNN;
  *(uint4*)p = o0;
  *(uint4*)(p + 4) = o1;
}

// ---------------------------------------------------------------------------
// Streaming bitonic merge of NC sorted 8-lists, keep smallest 8.
// Per chunk: 8 x min (half-cleaner vs reversed list) + 12-CE bitonic cleanup
// (skipped on the last chunk — consumer re-sorts by exact keys anyway).
// ---------------------------------------------------------------------------
template <int NC>
__device__ __forceinline__ void merge_list(const uint32_t* __restrict__ base, int i,
                                           uint32_t out[KNN]) {
  const uint32_t* p0 = base + (size_t)i * KNN;
  uint4 a = *(const uint4*)p0, bq = *(const uint4*)(p0 + 4);
  out[0] = a.x; out[1] = a.y; out[2] = a.z; out[3] = a.w;
  out[4] = bq.x; out[5] = bq.y; out[6] = bq.z; out[7] = bq.w;
#pragma unroll
  for (int c = 1; c < NC; ++c) {
    const uint32_t* pc = base + ((size_t)c * NPTS + (size_t)i) * KNN;
    const uint4 l0 = *(const uint4*)pc, l1 = *(const uint4*)(pc + 4);
    const uint32_t L[KNN] = {l0.x, l0.y, l0.z, l0.w, l1.x, l1.y, l1.z, l1.w};
    uint32_t t[KNN];
#pragma unroll
    for (int m = 0; m < KNN; ++m) t[m] = u32min(out[m], L[KNN - 1 - m]);
    if (c != NC - 1) {
      // bitonic cleanup: distances 4, 2, 1
#define CEU(x, y) { uint32_t lo = u32min(t[x], t[y]); uint32_t hi = u32max(t[x], t[y]); t[x] = lo; t[y] = hi; }
      CEU(0,4) CEU(1,5) CEU(2,6) CEU(3,7)
      CEU(0,2) CEU(1,3) CEU(4,6) CEU(5,7)
      CEU(0,1) CEU(2,3) CEU(4,5) CEU(6,7)
#undef CEU
    }
#pragma unroll
    for (int m = 0; m < KNN; ++m) out[m] = t[m];
  }
}

// Batcher odd-even mergesort for 8 elements: 19 compare-exchanges.
__device__ __forceinline__ void sort8(unsigned long long s[8]) {
#define CE(a, b) { unsigned long long lo = u64min(s[a], s[b]); \
                   unsigned long long hi = u64max(s[a], s[b]); s[a] = lo; s[b] = hi; }
  CE(0,1) CE(2,3) CE(0,2) CE(1,3) CE(1,2)
  CE(4,5) CE(6,7) CE(4,6) CE(5,7) CE(5,6)
  CE(0,4) CE(1,5) CE(2,6) CE(3,7)
  CE(2,4) CE(3,5)
  CE(1,2) CE(3,4) CE(5,6)
#undef CE
}

// ---------------------------------------------------------------------------
// Kernel 2: merge partial lists, recompute exact distances with the
// reference's sq_i + sq_j - 2*dot formula, re-sort by exact (dist, idx),
// compute loss terms, wave-reduce, one atomic per block (block = 1 wave).
// ---------------------------------------------------------------------------
template <int NC>
__global__ void __launch_bounds__(64)
loss_t(const float* __restrict__ pred, const float* __restrict__ tgt,
       const uint32_t* __restrict__ partial, double* __restrict__ acc) {
  const int p = blockIdx.x * 64 + threadIdx.x;   // 0 .. 16383
  const int b = p >> 12;
  const int i = p & (NPTS - 1);

  const float* __restrict__ P = pred + (size_t)b * NPTS * 3;
  const float* __restrict__ T = tgt  + (size_t)b * NPTS * 3;

  uint32_t mp[KNN], mt[KNN];
  merge_list<NC>(partial + (size_t)(0 * BATCH + b) * NC * NPTS * KNN, i, mp);
  merge_list<NC>(partial + (size_t)(1 * BATCH + b) * NC * NPTS * KNN, i, mt);

  const float pix = P[3 * i], piy = P[3 * i + 1], piz = P[3 * i + 2];
  const float tix = T[3 * i], tiy = T[3 * i + 1], tiz = T[3 * i + 2];
  const float sqp = pix * pix + piy * piy + piz * piz;
  const float sqt = tix * tix + tiy * tiy + tiz * tiz;

  // Exact sort keys: (float_bits(dist) << 12) | idx — monotone in (dist, idx).
  unsigned long long kp[KNN], kt[KNN];
#pragma unroll
  for (int k = 0; k < KNN; ++k) {
    {
      const int j = (int)(mp[k] & 0xFFFu);
      const float x = P[3 * j], y = P[3 * j + 1], z = P[3 * j + 2];
      const float d2 = sqp + (x * x + y * y + z * z)
                       - 2.0f * (pix * x + piy * y + piz * z);
      const float dist = sqrtf(fmaxf(d2, EPS_F));
      kp[k] = ((unsigned long long)__float_as_uint(dist) << 12) | (unsigned long long)j;
    }
    {
      const int j = (int)(mt[k] & 0xFFFu);
      const float x = T[3 * j], y = T[3 * j + 1], z = T[3 * j + 2];
      const float d2 = sqt + (x * x + y * y + z * z)
                       - 2.0f * (tix * x + tiy * y + tiz * z);
      const float dist = sqrtf(fmaxf(d2, EPS_F));
      kt[k] = ((unsigned long long)__float_as_uint(dist) << 12) | (unsigned long long)j;
    }
  }
  sort8(kp);
  sort8(kt);

  float dsp = 0.f, dst = 0.f, sdot = 0.f;
  float pxx = 0, pyy = 0, pzz = 0, pxy = 0, pxz = 0, pyz = 0;
  float txx = 0, tyy = 0, tzz = 0, txy = 0, txz = 0, tyz = 0;
#pragma unroll
  for (int k = 0; k < KNN; ++k) {
    const int jp = (int)(kp[k] & 0xFFFu);
    dsp += __uint_as_float((uint32_t)(kp[k] >> 12));
    const float ax = P[3 * jp] - pix, ay = P[3 * jp + 1] - piy, az = P[3 * jp + 2] - piz;
    const float an = sqrtf(ax * ax + ay * ay + az * az);
    const float ai = 1.0f / fmaxf(an, EPS_F);
    pxx += ax * ax; pyy += ay * ay; pzz += az * az;
    pxy += ax * ay; pxz += ax * az; pyz += ay * az;

    const int jt = (int)(kt[k] & 0xFFFu);
    dst += __uint_as_float((uint32_t)(kt[k] >> 12));
    const float bxv = T[3 * jt] - tix, byv = T[3 * jt + 1] - tiy, bzv = T[3 * jt + 2] - tiz;
    const float bn = sqrtf(bxv * bxv + byv * byv + bzv * bzv);
    const float bi = 1.0f / fmaxf(bn, EPS_F);
    txx += bxv * bxv; tyy += byv * byv; tzz += bzv * bzv;
    txy += bxv * byv; txz += bxv * bzv; tyz += byv * bzv;

    sdot += (ax * bxv + ay * byv + az * bzv) * (ai * bi);
  }

  const float densp = dsp * (1.0f / KNN);
  const float denst = dst * (1.0f / KNN);
  float e = (densp - denst) * (densp - denst);

  const float dxx = (pxx - txx) * (1.0f / KNN);
  const float dyy = (pyy - tyy) * (1.0f / KNN);
  const float dzz = (pzz - tzz) * (1.0f / KNN);
  const float dxy = (pxy - txy) * (1.0f / KNN);
  const float dxz = (pxz - txz) * (1.0f / KNN);
  const float dyz = (pyz - tyz) * (1.0f / KNN);
  float cfro = sqrtf(dxx * dxx + dyy * dyy + dzz * dzz
                     + 2.0f * (dxy * dxy + dxz * dxz + dyz * dyz));
  float s = sdot;

  // One wave per block: shuffle-reduce, lane 0 atomics.
#pragma unroll
  for (int off = 32; off > 0; off >>= 1) {
    e    += __shfl_down(e, off);
    s    += __shfl_down(s, off);
    cfro += __shfl_down(cfro, off);
  }
  if (threadIdx.x == 0) {
    atomicAdd(&acc[0], (double)e);
    atomicAdd(&acc[1], (double)s);
    atomicAdd(&acc[2], (double)cfro);
  }
}

extern "C" __global__ void finalize_kernel(const double* __restrict__ acc,
                                           float* __restrict__ out) {
  const double BN = (double)BATCH * (double)NPTS;
  const double density   = acc[0] / BN;
  const double direction = 1.0 - acc[1] / (BN * (double)KNN);
  const double curvature = acc[2] / BN;
  out[0] = (float)(density + 0.5 * direction + 0.5 * curvature);
}

extern "C" void kernel_launch(void* const* d_in, const int* in_sizes, int n_in,
                              void* d_out, int out_size, void* d_ws, size_t ws_size,
                              hipStream_t stream) {
  const float* pred = (const float*)d_in[0];
  const float* tgt  = (const float*)d_in[1];
  double* acc = (double*)d_ws;
  uint32_t* partial = (uint32_t*)((char*)d_ws + 256);

  hipMemsetAsync(acc, 0, 32, stream);

  const size_t need16 = 256 + (size_t)2 * BATCH * 16 * NPTS * KNN * sizeof(uint32_t);
  if (ws_size >= need16) {
    knn_partial_t<16><<<2 * BATCH * (NPTS / 256) * 16, 256, 0, stream>>>(pred, tgt, partial);
    loss_t<16><<<(BATCH * NPTS) / 64, 64, 0, stream>>>(pred, tgt, partial, acc);
  } else {
    knn_partial_t<8><<<2 * BATCH * (NPTS / 256) * 8, 256, 0, stream>>>(pred, tgt, partial);
    loss_t<8><<<(BATCH * NPTS) / 64, 64, 0, stream>>>(pred, tgt, partial, acc);
  }
  finalize_kernel<<<1, 1, 0, stream>>>(acc, (float*)d_out);
}